// Round 2
// baseline (172.496 us; speedup 1.0000x reference)
//
#include <hip/hip_runtime.h>
#include <math.h>

// NetVLAD clustering layer, f32, MI355X.
// x:[16,256,1500], centroids:[64,256], lin_w:[66,256], lin_b:[66]
// out: [16, 64*256] f32
//
// R2 restructure: LDS-pipe was the bottleneck (broadcast operands through
// ds_read). Broadcast operands now go through the SCALAR pipe (s_load via
// wave-uniform addresses), LDS keeps only the lane-varying operand (x in K2).
//
//  K1: a[u,c,t] = softmax_c'(x·w+b)[c<64]; W via s_load, x via coalesced
//      global loads, f-reduction split across 4 waves, LDS tree-reduce tail.
//  K2: partial[chunk][u][c][f] = sum_{t in chunk} a*x; a via s_load, x tile
//      in LDS (row stride 100 floats = 25 odd 16B units -> conflict-free
//      ds_read_b128), f split across 2 block-halves -> 512 blocks (2/CU).
//  K3: comp = sum partials - asum*centroid; intra-normalize rows.
//  K4: global L2 normalize.

#define NU 16
#define NF 256
#define NT 1500
#define NC 64
#define NCG 66
#define EPSN 1e-12f

#define T_CHUNK 96
#define N_CHUNKS 16   // ceil(1500/96); last chunk has 60 t

// ---------------- helpers ----------------
__device__ __forceinline__ float blk_reduce_sum(float v, float* sbuf) {
    #pragma unroll
    for (int off = 32; off > 0; off >>= 1) v += __shfl_down(v, off, 64);
    const int lane = threadIdx.x & 63, wv = threadIdx.x >> 6;
    if (lane == 0) sbuf[wv] = v;
    __syncthreads();
    float r = sbuf[0] + sbuf[1] + sbuf[2] + sbuf[3];
    __syncthreads();
    return r;
}

// ---------------- K1: assignments ----------------
// grid (24, 16), block 256. lane = t, wave w reduces features [64w,64w+64).
// W reads are wave-uniform -> s_load_dwordx4 (scalar pipe, no LDS traffic).
__global__ __launch_bounds__(256) void k1_assign(
        const float* __restrict__ x, const float* __restrict__ lin_w,
        const float* __restrict__ lin_b, float* __restrict__ a_ws) {
    const int u    = blockIdx.y;
    const int t0   = blockIdx.x * 64;
    const int tid  = threadIdx.x;
    const int lane = tid & 63;
    const int wave = __builtin_amdgcn_readfirstlane(tid >> 6);
    const int t    = t0 + lane;
    const int tc   = (t < NT) ? t : (NT - 1);   // clamp loads; masked store

    __shared__ float red[2][NCG][64];

    float acc[NCG];
    #pragma unroll
    for (int c = 0; c < NCG; ++c) acc[c] = 0.0f;

    const float* wbase = lin_w + wave * 64;              // + c*NF + k, uniform
    const float* xbase = x + (u * NF + wave * 64) * NT + tc;

    #pragma unroll 2
    for (int kq = 0; kq < 16; ++kq) {                    // 16 quads of 4 feats
        float xv[4];
        #pragma unroll
        for (int q = 0; q < 4; ++q) xv[q] = xbase[(kq * 4 + q) * NT];
        #pragma unroll
        for (int c = 0; c < NCG; ++c) {
            const float4 w = *(const float4*)(wbase + c * NF + kq * 4); // s_load
            acc[c] += w.x * xv[0] + w.y * xv[1] + w.z * xv[2] + w.w * xv[3];
        }
    }

    // tree reduce across the 4 waves (each holds a feature-quarter partial)
    if (wave >= 2) {
        #pragma unroll
        for (int c = 0; c < NCG; ++c) red[wave - 2][c][lane] = acc[c];
    }
    __syncthreads();
    if (wave < 2) {
        #pragma unroll
        for (int c = 0; c < NCG; ++c) acc[c] += red[wave][c][lane];
    }
    __syncthreads();
    if (wave == 1) {
        #pragma unroll
        for (int c = 0; c < NCG; ++c) red[0][c][lane] = acc[c];
    }
    __syncthreads();
    if (wave == 0) {
        #pragma unroll
        for (int c = 0; c < NCG; ++c) acc[c] += red[0][c][lane] + lin_b[c];
        float m = -INFINITY;
        #pragma unroll
        for (int c = 0; c < NCG; ++c) m = fmaxf(m, acc[c]);
        float s = 0.0f;
        #pragma unroll
        for (int c = 0; c < NCG; ++c) { acc[c] = __expf(acc[c] - m); s += acc[c]; }
        const float inv = 1.0f / s;
        if (t < NT) {
            #pragma unroll
            for (int c = 0; c < NC; ++c)
                a_ws[(u * NC + c) * NT + t] = acc[c] * inv;   // coalesced per c
        }
    }
}

// ---------------- K2: aggregation GEMM partials ----------------
// grid (N_CHUNKS, 2, 16): chunk, f-half, u. 256 threads.
// Block computes 64c x 128f for one 96-t chunk. a via s_load (scalar pipe),
// x tile in LDS, stride 100 floats (odd in 16B units -> b128 conflict-free).
// Thread tile 16c x 2f; per k-quad: 2 ds_read_b128 + 16 s_load_dwordx4 + 128 FMA.
__global__ __launch_bounds__(256) void k2_agg(
        const float* __restrict__ x, const float* __restrict__ a_ws,
        float* __restrict__ partial) {
    const int chunk = blockIdx.x;
    const int fh    = blockIdx.y;          // f-half: 0 or 1
    const int u     = blockIdx.z;
    const int t0    = chunk * T_CHUNK;
    const int nt    = min(T_CHUNK, NT - t0);   // 96 or 60
    const int tid   = threadIdx.x;

    __shared__ float Xsm[128][T_CHUNK + 4];    // stride 100 floats

    // stage x[fh*128 + 0..127][t0..t0+nt) -> Xsm  (4 lanes per row = 64B segs)
    const int r0 = tid >> 2, l4 = tid & 3;
    #pragma unroll
    for (int g = 0; g < 2; ++g) {
        const int fr = r0 + 64 * g;
        const float* rp = x + (u * NF + fh * 128 + fr) * NT + t0;
        #pragma unroll
        for (int s = 0; s < 6; ++s) {
            const int col = (l4 + 4 * s) * 4;   // 0..92, float offset
            float4 v;
            if (col + 4 <= nt) v = *(const float4*)(rp + col);
            else {
                v.x = (col + 0 < nt) ? rp[col + 0] : 0.0f;
                v.y = (col + 1 < nt) ? rp[col + 1] : 0.0f;
                v.z = (col + 2 < nt) ? rp[col + 2] : 0.0f;
                v.w = (col + 3 < nt) ? rp[col + 3] : 0.0f;
            }
            *(float4*)&Xsm[fr][col] = v;
        }
    }
    __syncthreads();

    const int wv = __builtin_amdgcn_readfirstlane(tid >> 6);
    const int c0 = wv * 16;                // this wave's 16 clusters
    const int fl = tid & 63;               // f_local = fl + 64*j, j<2

    float acc[16][2];
    #pragma unroll
    for (int i = 0; i < 16; ++i) { acc[i][0] = 0.0f; acc[i][1] = 0.0f; }

    const float* abase = a_ws + (u * NC + c0) * NT + t0;   // uniform
    const int kq_end = nt >> 2;            // 24 or 15

    for (int kq = 0; kq < kq_end; ++kq) {
        float4 xv[2];
        #pragma unroll
        for (int j = 0; j < 2; ++j)
            xv[j] = *(const float4*)&Xsm[fl + 64 * j][kq * 4];   // ds_read_b128
        #pragma unroll
        for (int i = 0; i < 16; ++i) {
            const float4 a4 = *(const float4*)(abase + i * NT + kq * 4); // s_load
            #pragma unroll
            for (int j = 0; j < 2; ++j)
                acc[i][j] += a4.x * xv[j].x + a4.y * xv[j].y
                           + a4.z * xv[j].z + a4.w * xv[j].w;
        }
    }

    // write partials [chunk][u][c][f]
    #pragma unroll
    for (int i = 0; i < 16; ++i) {
        float* op = partial + ((chunk * NU + u) * NC + c0 + i) * NF + fh * 128;
        op[fl]      = acc[i][0];
        op[fl + 64] = acc[i][1];
    }
}

// ---------------- K3: reduce partials, subtract centroid term, intra-norm ----
// grid (64, 16), block 256 (one thread per f).
__global__ __launch_bounds__(256) void k3_norm(
        const float* __restrict__ a_ws, const float* __restrict__ partial,
        const float* __restrict__ centroids, float* __restrict__ compn,
        float* __restrict__ rowsq) {
    const int c = blockIdx.x, u = blockIdx.y;
    const int tid = threadIdx.x;
    __shared__ float sbuf[4];

    // asum[u][c] = sum_t a
    float s = 0.0f;
    const float* arow = a_ws + (u * NC + c) * NT;
    for (int i = tid; i < NT; i += 256) s += arow[i];
    const float asum = blk_reduce_sum(s, sbuf);

    float val = 0.0f;
    #pragma unroll
    for (int ch = 0; ch < N_CHUNKS; ++ch)
        val += partial[((ch * NU + u) * NC + c) * NF + tid];
    val -= asum * centroids[c * NF + tid];

    const float ss = blk_reduce_sum(val * val, sbuf);
    const float d  = fmaxf(sqrtf(ss), EPSN);
    compn[(u * NC + c) * NF + tid] = val / d;
    if (tid == 0) rowsq[u * NC + c] = ss / (d * d);
}

// ---------------- K4: global normalize ----------------
// grid (4, 16), block 256.
__global__ __launch_bounds__(256) void k4_scale(
        const float* __restrict__ compn, const float* __restrict__ rowsq,
        float* __restrict__ out) {
    const int u = blockIdx.y;
    const int tid = threadIdx.x;
    float gss = 0.0f;
    #pragma unroll
    for (int cc = 0; cc < NC; ++cc) gss += rowsq[u * NC + cc];  // uniform
    const float inv = 1.0f / fmaxf(sqrtf(gss), EPSN);
    const int base = u * (NC * NF) + blockIdx.x * 4096;
    #pragma unroll
    for (int r = 0; r < 16; ++r) {
        const int idx = base + r * 256 + tid;
        out[idx] = compn[idx] * inv;
    }
}

// ---------------- launcher ----------------
extern "C" void kernel_launch(void* const* d_in, const int* in_sizes, int n_in,
                              void* d_out, int out_size, void* d_ws, size_t ws_size,
                              hipStream_t stream) {
    (void)in_sizes; (void)n_in; (void)out_size; (void)ws_size;
    const float* x         = (const float*)d_in[0];
    const float* centroids = (const float*)d_in[1];
    const float* lin_w     = (const float*)d_in[2];
    const float* lin_b     = (const float*)d_in[3];
    float* out = (float*)d_out;

    float* ws      = (float*)d_ws;
    float* a_ws    = ws;                                   // 16*64*1500
    float* partial = a_ws + NU * NC * NT;                  // 16*16*64*256
    float* compn   = partial + N_CHUNKS * NU * NC * NF;    // 262,144
    float* rowsq   = compn + NU * NC * NF;                 // 1,024

    dim3 blk(256);
    hipLaunchKernelGGL(k1_assign, dim3(24, NU), blk, 0, stream, x, lin_w, lin_b, a_ws);
    hipLaunchKernelGGL(k2_agg,    dim3(N_CHUNKS, 2, NU), blk, 0, stream, x, a_ws, partial);
    hipLaunchKernelGGL(k3_norm,   dim3(NC, NU), blk, 0, stream, a_ws, partial, centroids, compn, rowsq);
    hipLaunchKernelGGL(k4_scale,  dim3(4, NU), blk, 0, stream, compn, rowsq, out);
}